// Round 15
// baseline (67.843 us; speedup 1.0000x reference)
//
#include <hip/hip_runtime.h>

#define N_NODES 40000
#define D 128
#define N_EDGES 640000
#define GRP 128      // dst nodes per key group
#define NKEY 313     // ceil(N_NODES / GRP)
#define TSIZE 2048   // edges per tile
#define NTILE 313    // ceil(N_EDGES / TSIZE); tile 312 has 1024 edges
#define GCAP 2560    // epack/esrc16 capacity per key group (mean 2048, +11 sigma)
// src-degree histogram (proven rounds 7-14):
#define NSLICE 32
#define SLICE_E 20000
#define SLICE_E4 5000
#define HALF_BINS 20000
#define HALF_W 10000
#define WROW 20000
#define SRCH_BLKS 64
#define GEMM_BLKS 625  // x 64 nodes
#define XP 136         // bf16 x-tile pitch in shorts

typedef __attribute__((ext_vector_type(8))) short short8_t;
typedef __attribute__((ext_vector_type(4))) float float4_t;

static __device__ __forceinline__ unsigned short f2bf(float f) {
  unsigned u = __float_as_uint(f);
  return (unsigned short)((u + 0x7fffu + ((u >> 16) & 1u)) >> 16);  // RNE
}
static __device__ __forceinline__ float bf2f(unsigned short h) {
  return __uint_as_float(((unsigned)h) << 16);
}

// Inclusive Hillis-Steele scan over s[0..511]; 256 threads, 2 indices each.
static __device__ __forceinline__ void scan512(unsigned* s, int tid) {
  const int t2 = tid + 256;
#pragma unroll
  for (int off = 1; off < 512; off <<= 1) {
    unsigned a = (tid >= off) ? s[tid - off] : 0u;
    unsigned c = (t2 >= off) ? s[t2 - off] : 0u;
    __syncthreads();
    s[tid] += a;
    s[t2] += c;
    __syncthreads();
  }
}

// ---------------------------------------------------------------------------
// kA — three roles (round-14 proven), all heavy writes coalesced:
//  bid < 64         : src-hist slab, u16-packed LDS histogram.
//  t=bid-64, t%3==2 : tile-scatter: LDS key-hist, scan, ONE global atomicAdd
//                     per (tile,key), in-LDS key-sort, sequential run writes.
//  else             : MFMA GEMM: self-repack W, bf16 x stage, hb = bf16(x@W).
// ---------------------------------------------------------------------------
__global__ __launch_bounds__(256) void kA(
    const float* __restrict__ x, const float* __restrict__ W,
    const int* __restrict__ src, const int* __restrict__ dst,
    unsigned* __restrict__ slabS, unsigned* __restrict__ keycursor,
    unsigned* __restrict__ epack, unsigned short* __restrict__ hb) {
  __shared__ unsigned smem[12544];  // 50176 B union
  const int bid = blockIdx.x;
  const int tid = threadIdx.x;

  if (bid < SRCH_BLKS) {
    // ---------------- src histogram role (proven) ----------------
    const int b = bid >> 1;
    const int h = bid & 1;
    for (int i = tid; i < HALF_W; i += 256) smem[i] = 0;
    __syncthreads();
    const int4* p4 = (const int4*)(src + b * SLICE_E);
    const unsigned lo = (unsigned)(h * HALF_BINS);
    for (int it = tid; it < SLICE_E4; it += 256) {
      const int4 v = p4[it];
      unsigned u;
      u = (unsigned)v.x - lo; if (u < HALF_BINS) atomicAdd(&smem[u >> 1], 1u << ((u & 1) * 16));
      u = (unsigned)v.y - lo; if (u < HALF_BINS) atomicAdd(&smem[u >> 1], 1u << ((u & 1) * 16));
      u = (unsigned)v.z - lo; if (u < HALF_BINS) atomicAdd(&smem[u >> 1], 1u << ((u & 1) * 16));
      u = (unsigned)v.w - lo; if (u < HALF_BINS) atomicAdd(&smem[u >> 1], 1u << ((u & 1) * 16));
    }
    __syncthreads();
    unsigned* row = slabS + (size_t)b * WROW + h * HALF_W;
    for (int i = tid; i < HALF_W; i += 256) row[i] = smem[i];
    return;
  }

  const int t = bid - SRCH_BLKS;
  if (t % 3 == 2) {
    // ---------------- tile-scatter role (round-14 proven) ----------------
    const int cid = t / 3;  // 0..312
    unsigned* cnt = smem;            // [NKEY]
    unsigned* cur = smem + 320;      // [NKEY]
    int* dlt = (int*)(smem + 640);   // [NKEY] base - local_start
    unsigned* s = smem + 960;        // [512]
    unsigned* buf = smem + 1536;     // [TSIZE]
    const int t2 = tid + 256;
    if (tid < NKEY) cnt[tid] = 0;
    if (t2 < NKEY) cnt[t2] = 0;
    __syncthreads();

    const int e0 = cid * TSIZE;
    const int nE = (N_EDGES - e0) < TSIZE ? (N_EDGES - e0) : TSIZE;
    int4 sa, sb, da, db;
    const bool act = (tid * 8) < nE;
    if (act) {
      sa = *(const int4*)(src + e0 + tid * 8);
      sb = *(const int4*)(src + e0 + tid * 8 + 4);
      da = *(const int4*)(dst + e0 + tid * 8);
      db = *(const int4*)(dst + e0 + tid * 8 + 4);
      atomicAdd(&cnt[da.x >> 7], 1u);
      atomicAdd(&cnt[da.y >> 7], 1u);
      atomicAdd(&cnt[da.z >> 7], 1u);
      atomicAdd(&cnt[da.w >> 7], 1u);
      atomicAdd(&cnt[db.x >> 7], 1u);
      atomicAdd(&cnt[db.y >> 7], 1u);
      atomicAdd(&cnt[db.z >> 7], 1u);
      atomicAdd(&cnt[db.w >> 7], 1u);
    }
    __syncthreads();

    const unsigned v0 = (tid < NKEY) ? cnt[tid] : 0u;
    const unsigned v1 = (t2 < NKEY) ? cnt[t2] : 0u;
    s[tid] = v0;
    s[t2] = v1;
    __syncthreads();
    scan512(s, tid);
    if (tid < NKEY) {
      const unsigned ex = s[tid] - v0;
      cur[tid] = ex;
      if (v0 > 0) dlt[tid] = (int)atomicAdd(&keycursor[tid], v0) - (int)ex;
    }
    if (t2 < NKEY) {
      const unsigned ex = s[t2] - v1;
      cur[t2] = ex;
      if (v1 > 0) dlt[t2] = (int)atomicAdd(&keycursor[t2], v1) - (int)ex;
    }
    __syncthreads();

    if (act) {
#define TPLACE(DV, SV)                                                \
  {                                                                   \
    const unsigned d_ = (unsigned)(DV);                               \
    const unsigned r_ = atomicAdd(&cur[d_ >> 7], 1u);                 \
    buf[r_] = (d_ << 16) | (unsigned)(SV);                            \
  }
      TPLACE(da.x, sa.x) TPLACE(da.y, sa.y) TPLACE(da.z, sa.z) TPLACE(da.w, sa.w)
      TPLACE(db.x, sb.x) TPLACE(db.y, sb.y) TPLACE(db.z, sb.z) TPLACE(db.w, sb.w)
#undef TPLACE
    }
    __syncthreads();
    for (int i = tid; i < nE; i += 256) {
      const unsigned p = buf[i];
      const unsigned key = (p >> 16) >> 7;
      const int off = i + dlt[key];
      if (off < GCAP) epack[(size_t)key * GCAP + off] = p;
    }
    return;
  }

  // ---------------- MFMA GEMM role (round-12/14 proven) ----------------
  const int gid = 2 * (t / 3) + (t % 3);
  if (gid >= GEMM_BLKS) return;
  const int n0 = gid * 64;
  const int w = tid >> 6;
  const int lane = tid & 63;

  unsigned short* wb = (unsigned short*)smem;  // 16384 shorts = 32 KB
  unsigned short* xb = wb + 16384;             // 64 x XP shorts

#pragma unroll 4
  for (int i = 0; i < 16; ++i) {
    const int g4 = i * 256 + tid;
    const int k = g4 >> 5;
    const int d0 = (g4 & 31) * 4;
    const float4 v = ((const float4*)W)[g4];
    const int q = k >> 5, r = k & 31;
    const int base =
        (((d0 >> 4) * 4 + q) * 64 + ((r >> 3) * 16 + (d0 & 15))) * 8 + (r & 7);
    wb[base] = f2bf(v.x);
    wb[base + 8] = f2bf(v.y);
    wb[base + 16] = f2bf(v.z);
    wb[base + 24] = f2bf(v.w);
  }

  {
    const float4* xg = (const float4*)(x + (size_t)n0 * D);
#pragma unroll
    for (int j = 0; j < 8; ++j) {
      const int idx = tid + j * 256;
      const int row = idx >> 5;
      const int c4 = idx & 31;
      const float4 v = xg[idx];
      ushort4 o;
      o.x = f2bf(v.x); o.y = f2bf(v.y); o.z = f2bf(v.z); o.w = f2bf(v.w);
      *(ushort4*)(xb + row * XP + c4 * 4) = o;
    }
  }
  __syncthreads();

  short8_t afrag[4];
  {
    const unsigned short* ap0 = xb + (w * 16 + (lane & 15)) * XP + (lane >> 4) * 8;
#pragma unroll
    for (int q = 0; q < 4; ++q) afrag[q] = *(const short8_t*)(ap0 + q * 32);
  }

  const int orow = n0 + w * 16 + (lane >> 4) * 4;
  const int ocolbase = lane & 15;
#pragma unroll
  for (int t8 = 0; t8 < 8; ++t8) {
    float4_t acc = {0.f, 0.f, 0.f, 0.f};
#pragma unroll
    for (int q = 0; q < 4; ++q) {
      const short8_t bfrag = *(const short8_t*)(wb + ((t8 * 4 + q) * 64 + lane) * 8);
      acc = __builtin_amdgcn_mfma_f32_16x16x32_bf16(afrag[q], bfrag, acc, 0, 0, 0);
    }
    const int col = t8 * 16 + ocolbase;
#pragma unroll
    for (int r = 0; r < 4; ++r)
      hb[(size_t)(orow + r) * D + col] = f2bf(acc[r]);
  }
}

// ---------------------------------------------------------------------------
// kB — two roles (round-14 proven):
//  bid < 313 : group-CSR: contiguous epack reads, LDS hist(128) -> scan ->
//              offs/cnt_dst, place into block-private esrc16 region.
//  bid >= 313: dinv colsum from src slab.
// ---------------------------------------------------------------------------
__global__ __launch_bounds__(256) void kB(
    const unsigned* __restrict__ keycursor, const unsigned* __restrict__ epack,
    const unsigned* __restrict__ slabS, int* __restrict__ offs,
    int* __restrict__ cnt_dst, unsigned short* __restrict__ esrc16,
    float* __restrict__ dinv) {
  const int bid = blockIdx.x;
  const int tid = threadIdx.x;

  if (bid < NKEY) {
    const int k = bid;
    __shared__ unsigned cnt[GRP];
    __shared__ unsigned cur[GRP];
    __shared__ unsigned s[256];

    unsigned used = keycursor[k];
    if (used > GCAP) used = GCAP;
    const size_t base = (size_t)k * GCAP;

    if (tid < GRP) cnt[tid] = 0;
    __syncthreads();

    for (unsigned i = tid; i < used; i += 256) {
      atomicAdd(&cnt[(epack[base + i] >> 16) & 127], 1u);
    }
    __syncthreads();

    const unsigned v = (tid < GRP) ? cnt[tid] : 0u;
    s[tid] = v;
    __syncthreads();
#pragma unroll
    for (int off = 1; off < 256; off <<= 1) {
      unsigned a = (tid >= off) ? s[tid - off] : 0u;
      __syncthreads();
      s[tid] += a;
      __syncthreads();
    }
    if (tid < GRP) {
      const unsigned ex = s[tid] - v;
      cur[tid] = ex;
      const int n = k * GRP + tid;
      if (n < N_NODES) {
        offs[n] = (int)(base + ex);
        cnt_dst[n] = (int)v;
      }
    }
    __syncthreads();

    for (unsigned i = tid; i < used; i += 256) {
      const unsigned p = epack[base + i];
      const unsigned dl = (p >> 16) & 127;
      const unsigned r = atomicAdd(&cur[dl], 1u);
      esrc16[base + r] = (unsigned short)(p & 0xFFFFu);
    }
    return;
  }

  const int w = (bid - NKEY) * 256 + tid;
  if (w >= WROW) return;
  unsigned run = 0;
#pragma unroll 8
  for (int b = 0; b < NSLICE; ++b) run += slabS[(size_t)b * WROW + w];
  const unsigned lo = run & 0xFFFFu;
  const unsigned hi = run >> 16;
  dinv[2 * w] = lo ? 1.0f / (float)lo : 0.0f;
  dinv[2 * w + 1] = hi ? 1.0f / (float)hi : 0.0f;
}

// ---------------------------------------------------------------------------
// k4b — shuffle-batched gather, 16-deep: lane j caches edge j's (src, dinv);
// a node's up-to-32 edges are serviced by at most TWO 16-load rounds
// (vs four 8-load rounds in round 14) — latency fix, traffic unchanged.
// ---------------------------------------------------------------------------
__global__ __launch_bounds__(256) void k4b(
    const int* __restrict__ offs, const int* __restrict__ cnt_dst,
    const float* __restrict__ dinv, const unsigned short* __restrict__ esrc16,
    const unsigned short* __restrict__ hb,
    const float* __restrict__ b, float* __restrict__ out) {
  const int tid = threadIdx.x;
  const int node = blockIdx.x * 8 + (tid >> 5);
  const int lane = tid & 31;

  const int start = offs[node];
  const int len = cnt_dst[node];
  const unsigned short* bk = esrc16 + start;

  int sj = 0;
  if (lane < len) sj = bk[lane];
  const float fj = dinv[sj];

  float4 aa[4];
#pragma unroll
  for (int q = 0; q < 4; ++q) aa[q] = make_float4(0.f, 0.f, 0.f, 0.f);

  const int l32 = len < 32 ? len : 32;
  for (int jj = 0; jj < l32; jj += 16) {
    ushort4 u[16];
    float fq[16];
#pragma unroll
    for (int q = 0; q < 16; ++q) {
      const int j = jj + q;
      const int s = __shfl(sj, j, 32);
      const float f = __shfl(fj, j, 32);
      const bool on = j < l32;
      const int ss = on ? s : 0;
      u[q] = ((const ushort4*)(hb + (size_t)ss * D))[lane];  // row 0 if off
      fq[q] = on ? f : 0.0f;
    }
#pragma unroll
    for (int q = 0; q < 16; ++q) {
      const float f = fq[q];
      float4& a = aa[q & 3];
      a.x += f * bf2f(u[q].x);
      a.y += f * bf2f(u[q].y);
      a.z += f * bf2f(u[q].z);
      a.w += f * bf2f(u[q].w);
    }
  }
  // rare tail: in-degree > 32 (P ~ 1e-4)
  for (int j = 32; j < len; ++j) {
    const int s = bk[j];
    const float f = dinv[s];
    ushort4 u = ((const ushort4*)(hb + (size_t)s * D))[lane];
    aa[0].x += f * bf2f(u.x);
    aa[0].y += f * bf2f(u.y);
    aa[0].z += f * bf2f(u.z);
    aa[0].w += f * bf2f(u.w);
  }

  const float4 bias = ((const float4*)b)[lane];
  float4 v;
  v.x = bias.x + (aa[0].x + aa[1].x) + (aa[2].x + aa[3].x);
  v.y = bias.y + (aa[0].y + aa[1].y) + (aa[2].y + aa[3].y);
  v.z = bias.z + (aa[0].z + aa[1].z) + (aa[2].z + aa[3].z);
  v.w = bias.w + (aa[0].w + aa[1].w) + (aa[2].w + aa[3].w);
  ((float4*)(out + (size_t)node * D))[lane] = v;
}

extern "C" void kernel_launch(void* const* d_in, const int* in_sizes, int n_in,
                              void* d_out, int out_size, void* d_ws, size_t ws_size,
                              hipStream_t stream) {
  const float* x = (const float*)d_in[0];
  const float* W = (const float*)d_in[1];
  const float* b = (const float*)d_in[2];
  const int* ei = (const int*)d_in[3];
  const int* src = ei;            // edge_index[0]
  const int* dst = ei + N_EDGES;  // edge_index[1]
  float* out = (float*)d_out;

  char* ws = (char*)d_ws;
  float* dinv = (float*)(ws + 0);                          // 160,000
  unsigned* slabS = (unsigned*)(ws + 160000);              // 2,560,000
  unsigned* keycursor = (unsigned*)(ws + 2720000);         // 1,252 (+pad)
  unsigned* epack = (unsigned*)(ws + 2724096);             // 3,205,120
  int* offs = (int*)(ws + 5929216);                        // 160,000
  int* cnt_dst = (int*)(ws + 6089216);                     // 160,000
  unsigned short* esrc16 = (unsigned short*)(ws + 6249216);// 1,602,560
  unsigned short* hb = (unsigned short*)(ws + 7851776);    // 10,240,000 (18.1 MB)

  hipMemsetAsync(keycursor, 0, NKEY * 4, stream);
  kA<<<SRCH_BLKS + 939, 256, 0, stream>>>(x, W, src, dst, slabS, keycursor,
                                          epack, hb);
  kB<<<NKEY + 79, 256, 0, stream>>>(keycursor, epack, slabS, offs, cnt_dst,
                                    esrc16, dinv);
  k4b<<<5000, 256, 0, stream>>>(offs, cnt_dst, dinv, esrc16, hb, b, out);
}

// Round 16
// 62.955 us; speedup vs baseline: 1.0776x; 1.0776x over previous
//
#include <hip/hip_runtime.h>

#define N_NODES 40000
#define D 128
#define N_EDGES 640000
#define GRP 128      // dst nodes per key group
#define NKEY 313     // ceil(N_NODES / GRP)
#define TSIZE 2048   // edges per tile
#define NTILE 313    // ceil(N_EDGES / TSIZE); tile 312 has 1024 edges
#define GCAP 2560    // epack/esrc16 capacity per key group (mean 2048, +11 sigma)
// src-degree histogram (proven rounds 7-15):
#define NSLICE 32
#define SLICE_E 20000
#define SLICE_E4 5000
#define HALF_BINS 20000
#define HALF_W 10000
#define WROW 20000
#define SRCH_BLKS 64
#define GEMM_BLKS 625  // x 64 nodes
#define XP 136         // bf16 x-tile pitch in shorts

typedef __attribute__((ext_vector_type(8))) short short8_t;
typedef __attribute__((ext_vector_type(4))) float float4_t;

static __device__ __forceinline__ unsigned short f2bf(float f) {
  unsigned u = __float_as_uint(f);
  return (unsigned short)((u + 0x7fffu + ((u >> 16) & 1u)) >> 16);  // RNE
}
static __device__ __forceinline__ float bf2f(unsigned short h) {
  return __uint_as_float(((unsigned)h) << 16);
}

// Inclusive Hillis-Steele scan over s[0..511]; 256 threads, 2 indices each.
static __device__ __forceinline__ void scan512(unsigned* s, int tid) {
  const int t2 = tid + 256;
#pragma unroll
  for (int off = 1; off < 512; off <<= 1) {
    unsigned a = (tid >= off) ? s[tid - off] : 0u;
    unsigned c = (t2 >= off) ? s[t2 - off] : 0u;
    __syncthreads();
    s[tid] += a;
    s[t2] += c;
    __syncthreads();
  }
}

// ---------------------------------------------------------------------------
// kA — three roles (round-14 proven), all heavy writes coalesced:
//  bid < 64         : src-hist slab, u16-packed LDS histogram.
//  t=bid-64, t%3==2 : tile-scatter: LDS key-hist, scan, ONE global atomicAdd
//                     per (tile,key), in-LDS key-sort, sequential run writes.
//  else             : MFMA GEMM: self-repack W, bf16 x stage, hb = bf16(x@W).
// ---------------------------------------------------------------------------
__global__ __launch_bounds__(256) void kA(
    const float* __restrict__ x, const float* __restrict__ W,
    const int* __restrict__ src, const int* __restrict__ dst,
    unsigned* __restrict__ slabS, unsigned* __restrict__ keycursor,
    unsigned* __restrict__ epack, unsigned short* __restrict__ hb) {
  __shared__ unsigned smem[12544];  // 50176 B union
  const int bid = blockIdx.x;
  const int tid = threadIdx.x;

  if (bid < SRCH_BLKS) {
    // ---------------- src histogram role (proven) ----------------
    const int b = bid >> 1;
    const int h = bid & 1;
    for (int i = tid; i < HALF_W; i += 256) smem[i] = 0;
    __syncthreads();
    const int4* p4 = (const int4*)(src + b * SLICE_E);
    const unsigned lo = (unsigned)(h * HALF_BINS);
    for (int it = tid; it < SLICE_E4; it += 256) {
      const int4 v = p4[it];
      unsigned u;
      u = (unsigned)v.x - lo; if (u < HALF_BINS) atomicAdd(&smem[u >> 1], 1u << ((u & 1) * 16));
      u = (unsigned)v.y - lo; if (u < HALF_BINS) atomicAdd(&smem[u >> 1], 1u << ((u & 1) * 16));
      u = (unsigned)v.z - lo; if (u < HALF_BINS) atomicAdd(&smem[u >> 1], 1u << ((u & 1) * 16));
      u = (unsigned)v.w - lo; if (u < HALF_BINS) atomicAdd(&smem[u >> 1], 1u << ((u & 1) * 16));
    }
    __syncthreads();
    unsigned* row = slabS + (size_t)b * WROW + h * HALF_W;
    for (int i = tid; i < HALF_W; i += 256) row[i] = smem[i];
    return;
  }

  const int t = bid - SRCH_BLKS;
  if (t % 3 == 2) {
    // ---------------- tile-scatter role (round-14 proven) ----------------
    const int cid = t / 3;  // 0..312
    unsigned* cnt = smem;            // [NKEY]
    unsigned* cur = smem + 320;      // [NKEY]
    int* dlt = (int*)(smem + 640);   // [NKEY] base - local_start
    unsigned* s = smem + 960;        // [512]
    unsigned* buf = smem + 1536;     // [TSIZE]
    const int t2 = tid + 256;
    if (tid < NKEY) cnt[tid] = 0;
    if (t2 < NKEY) cnt[t2] = 0;
    __syncthreads();

    const int e0 = cid * TSIZE;
    const int nE = (N_EDGES - e0) < TSIZE ? (N_EDGES - e0) : TSIZE;
    int4 sa, sb, da, db;
    const bool act = (tid * 8) < nE;
    if (act) {
      sa = *(const int4*)(src + e0 + tid * 8);
      sb = *(const int4*)(src + e0 + tid * 8 + 4);
      da = *(const int4*)(dst + e0 + tid * 8);
      db = *(const int4*)(dst + e0 + tid * 8 + 4);
      atomicAdd(&cnt[da.x >> 7], 1u);
      atomicAdd(&cnt[da.y >> 7], 1u);
      atomicAdd(&cnt[da.z >> 7], 1u);
      atomicAdd(&cnt[da.w >> 7], 1u);
      atomicAdd(&cnt[db.x >> 7], 1u);
      atomicAdd(&cnt[db.y >> 7], 1u);
      atomicAdd(&cnt[db.z >> 7], 1u);
      atomicAdd(&cnt[db.w >> 7], 1u);
    }
    __syncthreads();

    const unsigned v0 = (tid < NKEY) ? cnt[tid] : 0u;
    const unsigned v1 = (t2 < NKEY) ? cnt[t2] : 0u;
    s[tid] = v0;
    s[t2] = v1;
    __syncthreads();
    scan512(s, tid);
    if (tid < NKEY) {
      const unsigned ex = s[tid] - v0;
      cur[tid] = ex;
      if (v0 > 0) dlt[tid] = (int)atomicAdd(&keycursor[tid], v0) - (int)ex;
    }
    if (t2 < NKEY) {
      const unsigned ex = s[t2] - v1;
      cur[t2] = ex;
      if (v1 > 0) dlt[t2] = (int)atomicAdd(&keycursor[t2], v1) - (int)ex;
    }
    __syncthreads();

    if (act) {
#define TPLACE(DV, SV)                                                \
  {                                                                   \
    const unsigned d_ = (unsigned)(DV);                               \
    const unsigned r_ = atomicAdd(&cur[d_ >> 7], 1u);                 \
    buf[r_] = (d_ << 16) | (unsigned)(SV);                            \
  }
      TPLACE(da.x, sa.x) TPLACE(da.y, sa.y) TPLACE(da.z, sa.z) TPLACE(da.w, sa.w)
      TPLACE(db.x, sb.x) TPLACE(db.y, sb.y) TPLACE(db.z, sb.z) TPLACE(db.w, sb.w)
#undef TPLACE
    }
    __syncthreads();
    for (int i = tid; i < nE; i += 256) {
      const unsigned p = buf[i];
      const unsigned key = (p >> 16) >> 7;
      const int off = i + dlt[key];
      if (off < GCAP) epack[(size_t)key * GCAP + off] = p;
    }
    return;
  }

  // ---------------- MFMA GEMM role (round-12/14 proven) ----------------
  const int gid = 2 * (t / 3) + (t % 3);
  if (gid >= GEMM_BLKS) return;
  const int n0 = gid * 64;
  const int w = tid >> 6;
  const int lane = tid & 63;

  unsigned short* wb = (unsigned short*)smem;  // 16384 shorts = 32 KB
  unsigned short* xb = wb + 16384;             // 64 x XP shorts

#pragma unroll 4
  for (int i = 0; i < 16; ++i) {
    const int g4 = i * 256 + tid;
    const int k = g4 >> 5;
    const int d0 = (g4 & 31) * 4;
    const float4 v = ((const float4*)W)[g4];
    const int q = k >> 5, r = k & 31;
    const int base =
        (((d0 >> 4) * 4 + q) * 64 + ((r >> 3) * 16 + (d0 & 15))) * 8 + (r & 7);
    wb[base] = f2bf(v.x);
    wb[base + 8] = f2bf(v.y);
    wb[base + 16] = f2bf(v.z);
    wb[base + 24] = f2bf(v.w);
  }

  {
    const float4* xg = (const float4*)(x + (size_t)n0 * D);
#pragma unroll
    for (int j = 0; j < 8; ++j) {
      const int idx = tid + j * 256;
      const int row = idx >> 5;
      const int c4 = idx & 31;
      const float4 v = xg[idx];
      ushort4 o;
      o.x = f2bf(v.x); o.y = f2bf(v.y); o.z = f2bf(v.z); o.w = f2bf(v.w);
      *(ushort4*)(xb + row * XP + c4 * 4) = o;
    }
  }
  __syncthreads();

  short8_t afrag[4];
  {
    const unsigned short* ap0 = xb + (w * 16 + (lane & 15)) * XP + (lane >> 4) * 8;
#pragma unroll
    for (int q = 0; q < 4; ++q) afrag[q] = *(const short8_t*)(ap0 + q * 32);
  }

  const int orow = n0 + w * 16 + (lane >> 4) * 4;
  const int ocolbase = lane & 15;
#pragma unroll
  for (int t8 = 0; t8 < 8; ++t8) {
    float4_t acc = {0.f, 0.f, 0.f, 0.f};
#pragma unroll
    for (int q = 0; q < 4; ++q) {
      const short8_t bfrag = *(const short8_t*)(wb + ((t8 * 4 + q) * 64 + lane) * 8);
      acc = __builtin_amdgcn_mfma_f32_16x16x32_bf16(afrag[q], bfrag, acc, 0, 0, 0);
    }
    const int col = t8 * 16 + ocolbase;
#pragma unroll
    for (int r = 0; r < 4; ++r)
      hb[(size_t)(orow + r) * D + col] = f2bf(acc[r]);
  }
}

// ---------------------------------------------------------------------------
// kB — two roles:
//  bid < 313 : group-CSR, SINGLE global pass: stage the group's epack run in
//              LDS (<=10 KB), then hist(128) -> scan -> offs/cnt_dst and
//              place into block-private esrc16 region, all from LDS.
//  bid >= 313: dinv colsum from src slab (proven).
// ---------------------------------------------------------------------------
__global__ __launch_bounds__(256) void kB(
    const unsigned* __restrict__ keycursor, const unsigned* __restrict__ epack,
    const unsigned* __restrict__ slabS, int* __restrict__ offs,
    int* __restrict__ cnt_dst, unsigned short* __restrict__ esrc16,
    float* __restrict__ dinv) {
  const int bid = blockIdx.x;
  const int tid = threadIdx.x;

  if (bid < NKEY) {
    const int k = bid;
    __shared__ unsigned ebuf[GCAP];  // 10,240 B staged run
    __shared__ unsigned cnt[GRP];
    __shared__ unsigned cur[GRP];
    __shared__ unsigned s[256];

    unsigned used = keycursor[k];
    if (used > GCAP) used = GCAP;
    const size_t base = (size_t)k * GCAP;

    // stage run (the only global epack read)
    for (unsigned i = tid; i < used; i += 256) ebuf[i] = epack[base + i];
    if (tid < GRP) cnt[tid] = 0;
    __syncthreads();

    for (unsigned i = tid; i < used; i += 256) {
      atomicAdd(&cnt[(ebuf[i] >> 16) & 127], 1u);
    }
    __syncthreads();

    const unsigned v = (tid < GRP) ? cnt[tid] : 0u;
    s[tid] = v;
    __syncthreads();
#pragma unroll
    for (int off = 1; off < 256; off <<= 1) {
      unsigned a = (tid >= off) ? s[tid - off] : 0u;
      __syncthreads();
      s[tid] += a;
      __syncthreads();
    }
    if (tid < GRP) {
      const unsigned ex = s[tid] - v;
      cur[tid] = ex;
      const int n = k * GRP + tid;
      if (n < N_NODES) {
        offs[n] = (int)(base + ex);
        cnt_dst[n] = (int)v;
      }
    }
    __syncthreads();

    for (unsigned i = tid; i < used; i += 256) {
      const unsigned p = ebuf[i];
      const unsigned dl = (p >> 16) & 127;
      const unsigned r = atomicAdd(&cur[dl], 1u);
      esrc16[base + r] = (unsigned short)(p & 0xFFFFu);
    }
    return;
  }

  // ---------------- dinv colsum role (proven) ----------------
  const int w = (bid - NKEY) * 256 + tid;
  if (w >= WROW) return;
  unsigned run = 0;
#pragma unroll 8
  for (int b = 0; b < NSLICE; ++b) run += slabS[(size_t)b * WROW + w];
  const unsigned lo = run & 0xFFFFu;
  const unsigned hi = run >> 16;
  dinv[2 * w] = lo ? 1.0f / (float)lo : 0.0f;
  dinv[2 * w + 1] = hi ? 1.0f / (float)hi : 0.0f;
}

// ---------------------------------------------------------------------------
// k4b — round-14 proven shuffle-batched gather (8-deep): lane j caches edge
// j's (src, dinv); hb rows loaded in batches of 8 via shfl-broadcast,
// 4 rotating accumulators. (16-deep regressed: VGPR/occupancy — round 15.)
// ---------------------------------------------------------------------------
__global__ __launch_bounds__(256) void k4b(
    const int* __restrict__ offs, const int* __restrict__ cnt_dst,
    const float* __restrict__ dinv, const unsigned short* __restrict__ esrc16,
    const unsigned short* __restrict__ hb,
    const float* __restrict__ b, float* __restrict__ out) {
  const int tid = threadIdx.x;
  const int node = blockIdx.x * 8 + (tid >> 5);
  const int lane = tid & 31;

  const int start = offs[node];
  const int len = cnt_dst[node];
  const unsigned short* bk = esrc16 + start;

  int sj = 0;
  if (lane < len) sj = bk[lane];
  const float fj = dinv[sj];

  float4 aa[4];
#pragma unroll
  for (int q = 0; q < 4; ++q) aa[q] = make_float4(0.f, 0.f, 0.f, 0.f);

  const int l32 = len < 32 ? len : 32;
  for (int jj = 0; jj < l32; jj += 8) {
    ushort4 u[8];
    float fq[8];
#pragma unroll
    for (int q = 0; q < 8; ++q) {
      const int j = jj + q;
      const int s = __shfl(sj, j, 32);
      const float f = __shfl(fj, j, 32);
      const bool on = j < l32;
      const int ss = on ? s : 0;
      u[q] = ((const ushort4*)(hb + (size_t)ss * D))[lane];  // row 0 if off
      fq[q] = on ? f : 0.0f;
    }
#pragma unroll
    for (int q = 0; q < 8; ++q) {
      const float f = fq[q];
      float4& a = aa[q & 3];
      a.x += f * bf2f(u[q].x);
      a.y += f * bf2f(u[q].y);
      a.z += f * bf2f(u[q].z);
      a.w += f * bf2f(u[q].w);
    }
  }
  // rare tail: in-degree > 32 (P ~ 1e-4)
  for (int j = 32; j < len; ++j) {
    const int s = bk[j];
    const float f = dinv[s];
    ushort4 u = ((const ushort4*)(hb + (size_t)s * D))[lane];
    aa[0].x += f * bf2f(u.x);
    aa[0].y += f * bf2f(u.y);
    aa[0].z += f * bf2f(u.z);
    aa[0].w += f * bf2f(u.w);
  }

  const float4 bias = ((const float4*)b)[lane];
  float4 v;
  v.x = bias.x + (aa[0].x + aa[1].x) + (aa[2].x + aa[3].x);
  v.y = bias.y + (aa[0].y + aa[1].y) + (aa[2].y + aa[3].y);
  v.z = bias.z + (aa[0].z + aa[1].z) + (aa[2].z + aa[3].z);
  v.w = bias.w + (aa[0].w + aa[1].w) + (aa[2].w + aa[3].w);
  ((float4*)(out + (size_t)node * D))[lane] = v;
}

extern "C" void kernel_launch(void* const* d_in, const int* in_sizes, int n_in,
                              void* d_out, int out_size, void* d_ws, size_t ws_size,
                              hipStream_t stream) {
  const float* x = (const float*)d_in[0];
  const float* W = (const float*)d_in[1];
  const float* b = (const float*)d_in[2];
  const int* ei = (const int*)d_in[3];
  const int* src = ei;            // edge_index[0]
  const int* dst = ei + N_EDGES;  // edge_index[1]
  float* out = (float*)d_out;

  char* ws = (char*)d_ws;
  float* dinv = (float*)(ws + 0);                          // 160,000
  unsigned* slabS = (unsigned*)(ws + 160000);              // 2,560,000
  unsigned* keycursor = (unsigned*)(ws + 2720000);         // 1,252 (+pad)
  unsigned* epack = (unsigned*)(ws + 2724096);             // 3,205,120
  int* offs = (int*)(ws + 5929216);                        // 160,000
  int* cnt_dst = (int*)(ws + 6089216);                     // 160,000
  unsigned short* esrc16 = (unsigned short*)(ws + 6249216);// 1,602,560
  unsigned short* hb = (unsigned short*)(ws + 7851776);    // 10,240,000 (18.1 MB)

  hipMemsetAsync(keycursor, 0, NKEY * 4, stream);
  kA<<<SRCH_BLKS + 939, 256, 0, stream>>>(x, W, src, dst, slabS, keycursor,
                                          epack, hb);
  kB<<<NKEY + 79, 256, 0, stream>>>(keycursor, epack, slabS, offs, cnt_dst,
                                    esrc16, dinv);
  k4b<<<5000, 256, 0, stream>>>(offs, cnt_dst, dinv, esrc16, hb, b, out);
}